// Round 11
// baseline (6380121.484 us; speedup 1.0000x reference)
//
// StageNet MI355X r11: r6 skeleton (best, 1.60ms) + XCD-local fast path.
// One-time census of HW_REG_XCC_ID per WG (agent-scope, always correct); if all 12
// WGs of a batch-group share an XCD, the h/flag exchange uses plain stores +
// sc0-only loads (L2 coherence point, ~3-4x lower RT) instead of agent atomics.
// Group leader publishes a single verdict -> all WGs agree on the protocol.
#include <hip/hip_runtime.h>
#include <hip/hip_bf16.h>
#include <stdint.h>

#define B_  256
#define T_  400
#define D_  280
#define H_  384
#define L_  12
#define K_  10
#define G_  1560
#define NP_ 1568
#define NT_USED 98
#define NT_PAD  104

typedef __attribute__((ext_vector_type(8))) short  short8_t;
typedef __attribute__((ext_vector_type(4))) float  float4_t;

__device__ __forceinline__ unsigned short f2bf(float f) {
  union { __hip_bfloat16 h; unsigned short u; } cv;
  cv.h = __float2bfloat16(f);
  return cv.u;
}
__device__ __forceinline__ float bf2f_lo(uint32_t u) { return __uint_as_float(u << 16); }
__device__ __forceinline__ float bf2f_hi(uint32_t u) { return __uint_as_float(u & 0xffff0000u); }
__device__ __forceinline__ float sigm(float x) { return 1.f / (1.f + __expf(-x)); }
__device__ __forceinline__ float ftanh(float x) { return 1.f - 2.f / (__expf(2.f * x) + 1.f); }

__device__ __forceinline__ int perm_g(int p) {
  if (p < 0 || p >= 32 + 12 * 128) return -1;
  if (p < 24) return p;
  if (p < 32) return -1;
  int q = p - 32;
  int l = q >> 7, r = q & 127, jb = r >> 5, cc = r & 31;
  return 24 + ((jb * 12 + l) << 5) + cc;
}

// ---------------- P0a: build WkbF + bias ----------------
__global__ void k_build_wkbf(const float* __restrict__ Wk, const float* __restrict__ bk,
                             const float* __restrict__ Wr, const float* __restrict__ br,
                             uint4* __restrict__ wkbF, float* __restrict__ bias) {
  int idx  = blockIdx.x * 256 + threadIdx.x;
  int lane = idx & 63;
  int rest = idx >> 6;
  int kt = rest % 9, nt = rest / 9;
  if (nt >= NT_PAD) return;
  int p = nt * 16 + (lane & 15);
  int g = perm_g(p);
  int kbase = kt * 32 + ((lane >> 4) << 3);
  unsigned short v[8];
#pragma unroll
  for (int j = 0; j < 8; ++j) {
    int k = kbase + j;
    float val = 0.f;
    if (g >= 0) {
      if (k < 280)        val = Wk[(size_t)k * G_ + g];
      else if (k == 280)  val = Wk[(size_t)280 * G_ + g] + Wr[(size_t)384 * G_ + g];
    }
    v[j] = f2bf(val);
  }
  uint4 u;
  u.x = (uint32_t)v[0] | ((uint32_t)v[1] << 16);
  u.y = (uint32_t)v[2] | ((uint32_t)v[3] << 16);
  u.z = (uint32_t)v[4] | ((uint32_t)v[5] << 16);
  u.w = (uint32_t)v[6] | ((uint32_t)v[7] << 16);
  wkbF[(size_t)(nt * 9 + kt) * 64 + lane] = u;
  if (kt == 0 && (lane >> 4) == 0 && p < NP_)
    bias[p] = (g >= 0) ? (bk[g] + br[g]) : 0.f;
}

// ---------------- P0c: build WrF ----------------
__global__ void k_build_wrf(const float* __restrict__ Wr, uint4* __restrict__ wrF) {
  int idx  = blockIdx.x * 256 + threadIdx.x;
  int lane = idx & 63;
  int rest = idx >> 6;
  int kt = rest % 12, nt = rest / 12;
  if (nt >= NT_USED) return;
  int p = nt * 16 + (lane & 15);
  int g = perm_g(p);
  int kbase = kt * 32 + ((lane >> 4) << 3);
  unsigned short v[8];
#pragma unroll
  for (int j = 0; j < 8; ++j) {
    int k = kbase + j;
    float val = (g >= 0) ? Wr[(size_t)k * G_ + g] : 0.f;
    v[j] = f2bf(val);
  }
  uint4 u;
  u.x = (uint32_t)v[0] | ((uint32_t)v[1] << 16);
  u.y = (uint32_t)v[2] | ((uint32_t)v[3] << 16);
  u.z = (uint32_t)v[4] | ((uint32_t)v[5] << 16);
  u.w = (uint32_t)v[6] | ((uint32_t)v[7] << 16);
  wrF[(size_t)(nt * 12 + kt) * 64 + lane] = u;
}

// ---------------- P1: pre-projection GEMM ----------------
__global__ __launch_bounds__(256) void k_pre_gemm(
    const float* __restrict__ x, const float* __restrict__ timev,
    const uint4* __restrict__ wkbF, const float* __restrict__ bias,
    uint2* __restrict__ preF) {
  __shared__ unsigned short A_lds[128 * 40];
  __shared__ uint4 B_lds[8 * 64];
  const int tid = threadIdx.x;
  const int ntile = blockIdx.x;
  const int tm = blockIdx.y;
  const int t = tm >> 1, b0 = (tm & 1) << 7;
  const int wv = tid >> 6, lane = tid & 63;
  const int wr = wv >> 1, wc = wv & 1;
  float4_t acc[4][4];
#pragma unroll
  for (int fi = 0; fi < 4; ++fi)
#pragma unroll
    for (int fj = 0; fj < 4; ++fj) { acc[fi][fj][0]=0.f; acc[fi][fj][1]=0.f; acc[fi][fj][2]=0.f; acc[fi][fj][3]=0.f; }

  for (int kt = 0; kt < 9; ++kt) {
    {
      int mi = tid >> 1, half = tid & 1, kk0 = half * 16;
      int b = b0 + mi;
      const float* xrow = x + ((size_t)b * T_ + t) * D_;
      int k0 = kt * 32 + kk0;
      unsigned short* dst = &A_lds[mi * 40 + kk0];
      if (kt < 8) {
        float4 v0 = *(const float4*)(xrow + k0);
        float4 v1 = *(const float4*)(xrow + k0 + 4);
        float4 v2 = *(const float4*)(xrow + k0 + 8);
        float4 v3 = *(const float4*)(xrow + k0 + 12);
        dst[0]=f2bf(v0.x); dst[1]=f2bf(v0.y); dst[2]=f2bf(v0.z); dst[3]=f2bf(v0.w);
        dst[4]=f2bf(v1.x); dst[5]=f2bf(v1.y); dst[6]=f2bf(v1.z); dst[7]=f2bf(v1.w);
        dst[8]=f2bf(v2.x); dst[9]=f2bf(v2.y); dst[10]=f2bf(v2.z); dst[11]=f2bf(v2.w);
        dst[12]=f2bf(v3.x); dst[13]=f2bf(v3.y); dst[14]=f2bf(v3.z); dst[15]=f2bf(v3.w);
      } else {
#pragma unroll
        for (int e = 0; e < 16; ++e) {
          int k = k0 + e;
          float val = 0.f;
          if (k < 280)       val = xrow[k];
          else if (k == 280) val = timev[(size_t)b * T_ + t];
          dst[e] = f2bf(val);
        }
      }
    }
#pragma unroll
    for (int pz = 0; pz < 2; ++pz) {
      int fn = (tid >> 6) + pz * 4;
      int inner = tid & 63;
      int ntg = ntile * 8 + fn;
      B_lds[fn * 64 + inner] = wkbF[(size_t)(ntg * 9 + kt) * 64 + inner];
    }
    __syncthreads();
    short8_t a[4], bfr[4];
#pragma unroll
    for (int fi = 0; fi < 4; ++fi) {
      int m = wr * 64 + fi * 16 + (lane & 15);
      a[fi] = *(const short8_t*)&A_lds[m * 40 + ((lane >> 4) << 3)];
    }
#pragma unroll
    for (int fj = 0; fj < 4; ++fj) {
      uint4 u = B_lds[(wc * 4 + fj) * 64 + lane];
      bfr[fj] = *reinterpret_cast<short8_t*>(&u);
    }
#pragma unroll
    for (int fi = 0; fi < 4; ++fi)
#pragma unroll
      for (int fj = 0; fj < 4; ++fj)
        acc[fi][fj] = __builtin_amdgcn_mfma_f32_16x16x32_bf16(a[fi], bfr[fj], acc[fi][fj], 0, 0, 0);
    __syncthreads();
  }
#pragma unroll
  for (int fi = 0; fi < 4; ++fi)
#pragma unroll
    for (int fj = 0; fj < 4; ++fj) {
      int nt_g = ntile * 8 + wc * 4 + fj;
      if (nt_g < NT_USED) {
        int bg = (b0 >> 4) + wr * 4 + fi;
        float bv = bias[nt_g * 16 + (lane & 15)];
        unsigned short r0 = f2bf(acc[fi][fj][0] + bv);
        unsigned short r1 = f2bf(acc[fi][fj][1] + bv);
        unsigned short r2 = f2bf(acc[fi][fj][2] + bv);
        unsigned short r3 = f2bf(acc[fi][fj][3] + bv);
        uint2 u;
        u.x = (uint32_t)r0 | ((uint32_t)r1 << 16);
        u.y = (uint32_t)r2 | ((uint32_t)r3 << 16);
        preF[(((size_t)t * 16 + bg) * NT_USED + nt_g) * 64 + lane] = u;
      }
    }
}

// ---------------- Scan: 192 WGs, weights in LDS, XCD-local fast path ----------------
#define XOS 164
#define WLDS_B   (10 * 12 * 64 * 16)          // 122880
#define XOL_OFF  WLDS_B
#define CST_OFF  (XOL_OFF + 16 * XOS * 4)
#define FMV_OFF  (CST_OFF + 16 * 32 * 4)
#define IMV_OFF  (FMV_OFF + 64)
#define SMEM_B   (IMV_OFF + 64)               // 135616
__global__ __launch_bounds__(256, 1)
void k_scan(
    const uint2* __restrict__ preF, const uint4* __restrict__ wrF,
    uint32_t* __restrict__ hbuf, uint32_t* __restrict__ flags,
    uint32_t* __restrict__ xccid, uint32_t* __restrict__ verdict,
    float* __restrict__ hist_h, float* __restrict__ hist_dis) {
  extern __shared__ char smem[];
  uint4* wLDS = (uint4*)smem;
  float (*xoL)[XOS] = (float(*)[XOS])(smem + XOL_OFF);
  float (*cSt)[32]  = (float(*)[32])(smem + CST_OFF);
  float* fmv = (float*)(smem + FMV_OFF);
  float* imv = (float*)(smem + IMV_OFF);
  __shared__ int fastLDS;

  const int tid  = threadIdx.x;
  const int wv   = tid >> 6, lane = tid & 63;
  const int bid  = blockIdx.x;
  const int l_own = bid >> 4, bg = bid & 15;
  const int nT = (wv < 2) ? 3 : 2;
  int ltg[3], ntg[3];
#pragma unroll
  for (int i = 0; i < 3; ++i) {
    int lt = wv + 4 * i;
    ltg[i] = lt;
    ntg[i] = (lt < 2) ? lt : (2 + 8 * l_own + (lt - 2));
  }
  // publish this WG's XCC id (agent scope: always correct)
  uint32_t xcc;
  asm volatile("s_getreg_b32 %0, hwreg(HW_REG_XCC_ID)" : "=s"(xcc));
  if (tid == 0)
    __hip_atomic_store(&xccid[bg * 16 + l_own], xcc, __ATOMIC_RELAXED, __HIP_MEMORY_SCOPE_AGENT);
  // one-time: stage this WG's 10 weight tiles (120KB) into LDS (overlaps census)
#pragma unroll
  for (int i = 0; i < 3; ++i) {
    if (i < nT) {
#pragma unroll
      for (int kt = 0; kt < 12; ++kt)
        wLDS[(ltg[i] * 12 + kt) * 64 + lane] = wrF[(size_t)(ntg[i] * 12 + kt) * 64 + lane];
    }
  }
  { int b = tid >> 4, cp = tid & 15; cSt[b][cp * 2] = 0.f; cSt[b][cp * 2 + 1] = 0.f; }
  // census verdict: leader (l_own==0) decides; everyone reads the single verdict
  if (tid == 0) {
    if (l_own == 0) {
      uint32_t ids[12];
      bool all = false;
      int budget = 200000;
      while (!all && budget-- > 0) {
        all = true;
#pragma unroll
        for (int q = 0; q < 12; ++q) {
          ids[q] = __hip_atomic_load(&xccid[bg * 16 + q], __ATOMIC_RELAXED, __HIP_MEMORY_SCOPE_AGENT);
          if (ids[q] == 0xFFFFFFFFu) all = false;
        }
      }
      uint32_t v = all ? 1u : 0u;
      if (all) {
#pragma unroll
        for (int q = 1; q < 12; ++q) if (ids[q] != ids[0]) v = 0u;
      }
      __hip_atomic_store(&verdict[bg], v, __ATOMIC_RELAXED, __HIP_MEMORY_SCOPE_AGENT);
    }
    uint32_t v = 0xFFFFFFFFu;
    long budget = 20000000;
    while (v == 0xFFFFFFFFu && budget-- > 0)
      v = __hip_atomic_load(&verdict[bg], __ATOMIC_RELAXED, __HIP_MEMORY_SCOPE_AGENT);
    fastLDS = (v == 1u) ? 1 : 0;
  }
  __syncthreads();
  const bool fast = (fastLDS != 0);

  const int rr0 = lane >> 4;
  const int cN  = lane & 15;
  for (int t = 0; t < T_; ++t) {
    // h-independent: precomputed projection (in flight during poll)
    float4_t acc[3];
#pragma unroll
    for (int i = 0; i < 3; ++i) {
      if (i < nT) {
        uint2 p = preF[(((size_t)t * 16 + bg) * NT_USED + ntg[i]) * 64 + lane];
        acc[i][0] = bf2f_lo(p.x); acc[i][1] = bf2f_hi(p.x);
        acc[i][2] = bf2f_lo(p.y); acc[i][3] = bf2f_hi(p.y);
      }
    }
    // poll 12 contiguous flags
    if (t > 0) {
      const uint32_t need = (uint32_t)t;
      const bool lact = lane < 12;
      const uint32_t* fp = flags + bg * 32 + (lact ? lane : 0);
      int budget = 200000;
      bool ok = false;
      if (fast) {
        while (!ok && budget-- > 0) {
          uint32_t v;
          asm volatile("global_load_dword %0, %1, off sc0\n\ts_waitcnt vmcnt(0)"
                       : "=v"(v) : "v"(fp) : "memory");
          ok = __all(!lact || v >= need);
        }
      } else {
        while (!ok && budget-- > 0) {
          uint32_t v = __hip_atomic_load(fp, __ATOMIC_RELAXED, __HIP_MEMORY_SCOPE_AGENT);
          ok = __all(!lact || v >= need);
        }
      }
    }
    __builtin_amdgcn_sched_barrier(0);
    asm volatile("" ::: "memory");
    // load h as A-fragments
    const int slot = t & 1;
    short8_t af[12];
    if (fast) {
      uint4 hv[12];
#pragma unroll
      for (int kt = 0; kt < 12; ++kt) {
        const uint32_t* hp = hbuf + (((slot * 16 + bg) * 12 + kt) << 8) + lane * 4;
        asm volatile("global_load_dwordx4 %0, %1, off sc0" : "=v"(hv[kt]) : "v"(hp));
      }
      asm volatile("s_waitcnt vmcnt(0)" ::: "memory");
      __builtin_amdgcn_sched_barrier(0);
#pragma unroll
      for (int kt = 0; kt < 12; ++kt) {
        asm volatile("" : "+v"(hv[kt].x), "+v"(hv[kt].y), "+v"(hv[kt].z), "+v"(hv[kt].w));
        af[kt] = *reinterpret_cast<short8_t*>(&hv[kt]);
      }
    } else {
#pragma unroll
      for (int kt = 0; kt < 12; ++kt) {
        const unsigned long long* hp =
            (const unsigned long long*)(hbuf + (((slot * 16 + bg) * 12 + kt) << 8) + lane * 4);
        unsigned long long u0 = __hip_atomic_load(hp + 0, __ATOMIC_RELAXED, __HIP_MEMORY_SCOPE_AGENT);
        unsigned long long u1 = __hip_atomic_load(hp + 1, __ATOMIC_RELAXED, __HIP_MEMORY_SCOPE_AGENT);
        uint4 u;
        u.x = (uint32_t)u0; u.y = (uint32_t)(u0 >> 32);
        u.z = (uint32_t)u1; u.w = (uint32_t)(u1 >> 32);
        af[kt] = *reinterpret_cast<short8_t*>(&u);
      }
    }
    // xo GEMM from LDS weights
#pragma unroll
    for (int kt = 0; kt < 12; ++kt) {
#pragma unroll
      for (int i = 0; i < 3; ++i) {
        if (i < nT) {
          uint4 w = wLDS[(ltg[i] * 12 + kt) * 64 + lane];
          acc[i] = __builtin_amdgcn_mfma_f32_16x16x32_bf16(af[kt], *reinterpret_cast<short8_t*>(&w), acc[i], 0, 0, 0);
        }
      }
    }
#pragma unroll
    for (int i = 0; i < 3; ++i) {
      if (i < nT && ltg[i] < 10) {
#pragma unroll
        for (int r = 0; r < 4; ++r)
          xoL[rr0 * 4 + r][ltg[i] * 16 + cN] = acc[i][r];
      }
    }
    __syncthreads();
    // fm (tid 0..15) / im (tid 16..31) cumax on wave0
    if (tid < 32) {
      int b = tid & 15;
      int base = (tid < 16) ? 0 : 12;
      float v[12], mx = -1e30f;
#pragma unroll
      for (int j = 0; j < 12; ++j) { v[j] = xoL[b][base + j]; mx = fmaxf(mx, v[j]); }
      float e[12], s = 0.f;
#pragma unroll
      for (int j = 0; j < 12; ++j) { e[j] = __expf(v[j] - mx); s += e[j]; }
      float inv = 1.f / s;
      if (tid < 16) {
        float cum = 0.f, fml = 0.f, fsum = 0.f;
#pragma unroll
        for (int j = 0; j < 12; ++j) {
          cum += e[j] * inv;
          if (j == l_own) fml = cum;
          fsum += cum;
        }
        fmv[b] = fml;
        if (l_own == 0 && t >= T_ - K_)
          hist_dis[(t - (T_ - K_)) * B_ + bg * 16 + b] = 1.f - fsum * (1.f / 12.f);
      } else {
        float cum = 0.f, iml = 0.f;
#pragma unroll
        for (int j = 11; j >= 0; --j) {
          cum += e[j] * inv;
          if (j == l_own) iml = cum;
        }
        imv[b] = iml;
      }
    }
    __syncthreads();
    // gates + state update; store h slice + history
    {
      int b = tid >> 4, cp = tid & 15, c0 = cp << 1;
      float fm_ = fmv[b], im_ = imv[b], ov = fm_ * im_;
      uint32_t packed = 0;
      float hh[2];
#pragma unroll
      for (int e2 = 0; e2 < 2; ++e2) {
        int c = c0 + e2;
        float f  = sigm(xoL[b][32 + c]);
        float ii = sigm(xoL[b][64 + c]);
        float oo = sigm(xoL[b][96 + c]);
        float ci = ftanh(xoL[b][128 + c]);
        float cl = cSt[b][c];
        float cn = ov * (f * cl + ii * ci) + (fm_ - ov) * cl + (im_ - ov) * ci;
        cSt[b][c] = cn;
        float h = oo * ftanh(cn);
        hh[e2] = h;
        packed |= (uint32_t)f2bf(h) << (16 * e2);
      }
      int hl = b + ((c0 >> 3) << 4);
      int slot2 = (t + 1) & 1;
      uint32_t* hp = hbuf + (((slot2 * 16 + bg) * 12 + l_own) << 8) + hl * 4 + ((c0 & 7) >> 1);
      if (fast) *(volatile uint32_t*)hp = packed;   // plain store: write-through to XCD L2
      else __hip_atomic_store(hp, packed, __ATOMIC_RELAXED, __HIP_MEMORY_SCOPE_AGENT);
      if (t >= T_ - K_) {
        float* hd = hist_h + (((size_t)(t - (T_ - K_)) * B_) + bg * 16 + b) * H_ + l_own * 32 + c0;
        hd[0] = hh[0]; hd[1] = hh[1];
      }
    }
    __syncthreads();   // drains all waves' stores (vmcnt 0) before flag
    if (tid == 0 && t < T_ - 1) {
      uint32_t* fq = flags + bg * 32 + l_own;
      if (fast) *(volatile uint32_t*)fq = (uint32_t)(t + 1);
      else __hip_atomic_store(fq, (uint32_t)(t + 1), __ATOMIC_RELAXED, __HIP_MEMORY_SCOPE_AGENT);
    }
  }
}

// ---------------- E1: local_dis + theme ----------------
__global__ void k_epi1(const float* __restrict__ hist_dis, const float* __restrict__ hist_h,
                       const float* __restrict__ Ws, const float* __restrict__ bs,
                       const float* __restrict__ Wrs, const float* __restrict__ brs,
                       float* __restrict__ ldis, float* __restrict__ theme) {
  int b = blockIdx.x, tid = threadIdx.x;  // 64 threads
  __shared__ float ld_s[K_], mh[H_], t1[64];
  if (tid == 0) {
    float cum = 0.f, v[K_], mx = -1e30f;
#pragma unroll
    for (int k = 0; k < K_; ++k) { cum += hist_dis[k * B_ + b]; v[k] = cum; mx = fmaxf(mx, cum); }
    float e[K_], s = 0.f;
#pragma unroll
    for (int k = 0; k < K_; ++k) { e[k] = __expf(v[k] - mx); s += e[k]; }
    float inv = 1.f / s;
#pragma unroll
    for (int k = 0; k < K_; ++k) { float r = e[k] * inv; ld_s[k] = r; ldis[b * K_ + k] = r; }
  }
  __syncthreads();
  for (int h = tid; h < H_; h += 64) {
    float a = 0.f;
#pragma unroll
    for (int k = 0; k < K_; ++k) a += hist_h[((size_t)k * B_ + b) * H_ + h] * ld_s[k];
    mh[h] = a * 0.1f;
  }
  __syncthreads();
  {
    float a = bs[tid];
    for (int h = 0; h < H_; ++h) a += mh[h] * Ws[h * 64 + tid];
    t1[tid] = fmaxf(a, 0.f);
  }
  __syncthreads();
  for (int o = tid; o < H_; o += 64) {
    float a = brs[o];
#pragma unroll 8
    for (int j = 0; j < 64; ++j) a += t1[j] * Wrs[j * H_ + o];
    theme[b * H_ + o] = sigm(a);
  }
}

// ---------------- E2: conv ----------------
__global__ __launch_bounds__(256) void k_epi2(const float* __restrict__ hist_h,
                                              const float* __restrict__ ldis,
                                              const float* __restrict__ Wc,
                                              const float* __restrict__ bc,
                                              float* __restrict__ convb) {
  __shared__ float lh_s[16][644];
  int og = blockIdx.x, bgp = blockIdx.y, tid = threadIdx.x;
  int b_l = tid & 15, o_l = tid >> 4;
  int b = bgp * 16 + b_l, o = og * 16 + o_l;
  float acc = 0.f;
  for (int c0 = 0; c0 < H_; c0 += 64) {
    __syncthreads();
    for (int it = tid; it < 16 * 64 * K_; it += 256) {
      int bb = it / 640, rem = it % 640, cc = rem / K_, k = rem % K_;
      lh_s[bb][cc * K_ + k] =
          hist_h[((size_t)k * B_ + bgp * 16 + bb) * H_ + c0 + cc] * ldis[(bgp * 16 + bb) * K_ + k];
    }
    __syncthreads();
    const float* wp = Wc + ((size_t)o * H_ + c0) * K_;
    for (int cc = 0; cc < 64; ++cc) {
#pragma unroll
      for (int k = 0; k < K_; ++k) acc += lh_s[b_l][cc * K_ + k] * wp[cc * K_ + k];
    }
  }
  convb[b * H_ + o] = acc + bc[o];
}

// ---------------- E3: final ----------------
__global__ void k_epi3(const float* __restrict__ theme, const float* __restrict__ convb,
                       const float* __restrict__ hist_h, const float* __restrict__ Wo,
                       const float* __restrict__ bo, float* __restrict__ out) {
  int b = blockIdx.x, tid = threadIdx.x;  // 384 threads
  __shared__ float part[6];
  float hfin = hist_h[((size_t)(K_ - 1) * B_ + b) * H_ + tid];
  float v = (theme[b * H_ + tid] * convb[b * H_ + tid] + hfin) * Wo[tid];
#pragma unroll
  for (int off = 32; off >= 1; off >>= 1) v += __shfl_down(v, off, 64);
  if ((tid & 63) == 0) part[tid >> 6] = v;
  __syncthreads();
  if (tid == 0) {
    float s = part[0] + part[1] + part[2] + part[3] + part[4] + part[5];
    out[b] = sigm(s + bo[0]);
  }
}

// ---------------- host ----------------
extern "C" void kernel_launch(void* const* d_in, const int* in_sizes, int n_in,
                              void* d_out, int out_size, void* d_ws, size_t ws_size,
                              hipStream_t stream) {
  const float* x    = (const float*)d_in[0];
  const float* tmv  = (const float*)d_in[1];
  const float* Wk   = (const float*)d_in[2];
  const float* bk   = (const float*)d_in[3];
  const float* Wr   = (const float*)d_in[4];
  const float* br   = (const float*)d_in[5];
  const float* Ws   = (const float*)d_in[6];
  const float* bs   = (const float*)d_in[7];
  const float* Wrs  = (const float*)d_in[8];
  const float* brs  = (const float*)d_in[9];
  const float* Wc   = (const float*)d_in[10];
  const float* bc   = (const float*)d_in[11];
  const float* Wo   = (const float*)d_in[12];
  const float* bo   = (const float*)d_in[13];

  char* ws = (char*)d_ws;
  size_t off = 0;
  auto alloc = [&](size_t bytes) { size_t o = off; off = (off + bytes + 255) & ~(size_t)255; return o; };
  const size_t PREF_B  = (size_t)T_ * 16 * NT_USED * 512;
  const size_t WKBF_B  = (size_t)NT_PAD * 9 * 1024;
  const size_t WRF_B   = (size_t)NT_USED * 12 * 1024;
  const size_t BIAS_B  = (size_t)NP_ * 4;
  const size_t HBUF_B  = (size_t)2 * 16 * 12 * 1024;
  const size_t FLAG_B  = (size_t)16 * 32 * 4;
  const size_t CEN_B   = (size_t)16 * 16 * 4 * 2;   // xccid[16][16] + verdict[16] (padded)
  const size_t HISTH_B = (size_t)K_ * B_ * H_ * 4;
  const size_t HISTD_B = (size_t)K_ * B_ * 4;
  const size_t LDIS_B  = (size_t)B_ * K_ * 4;
  const size_t THEME_B = (size_t)B_ * H_ * 4;
  const size_t CONV_B  = (size_t)B_ * H_ * 4;

  size_t o_pref  = alloc(PREF_B);
  size_t o_wkbf  = alloc(WKBF_B);
  size_t o_wrf   = alloc(WRF_B);
  size_t o_bias  = alloc(BIAS_B);
  size_t o_hbuf  = alloc(HBUF_B + FLAG_B);
  size_t o_flag  = o_hbuf + HBUF_B;
  size_t o_cen   = alloc(CEN_B);
  size_t o_hh    = alloc(HISTH_B);
  size_t o_hd    = alloc(HISTD_B);
  size_t o_ld    = alloc(LDIS_B);
  size_t o_th    = alloc(THEME_B);
  size_t o_cv    = alloc(CONV_B);
  if (ws_size < off) return;

  uint2*    preF  = (uint2*)(ws + o_pref);
  uint4*    wkbF  = (uint4*)(ws + o_wkbf);
  uint4*    wrF   = (uint4*)(ws + o_wrf);
  float*    bias  = (float*)(ws + o_bias);
  uint32_t* hbuf  = (uint32_t*)(ws + o_hbuf);
  uint32_t* flags = (uint32_t*)(ws + o_flag);
  uint32_t* xccid = (uint32_t*)(ws + o_cen);
  uint32_t* verd  = (uint32_t*)(ws + o_cen + 16 * 16 * 4);
  float*    histh = (float*)(ws + o_hh);
  float*    histd = (float*)(ws + o_hd);
  float*    ldis  = (float*)(ws + o_ld);
  float*    theme = (float*)(ws + o_th);
  float*    convb = (float*)(ws + o_cv);

  hipMemsetAsync(ws + o_hbuf, 0, HBUF_B + FLAG_B, stream);
  hipMemsetAsync(ws + o_cen, 0xFF, CEN_B, stream);
  k_build_wkbf<<<(NT_PAD * 9 * 64) / 256, 256, 0, stream>>>(Wk, bk, Wr, br, wkbF, bias);
  k_build_wrf<<<(NT_USED * 12 * 64) / 256, 256, 0, stream>>>(Wr, wrF);
  k_pre_gemm<<<dim3(13, T_ * 2), 256, 0, stream>>>(x, tmv, wkbF, bias, preF);
  k_scan<<<192, 256, SMEM_B, stream>>>(preF, wrF, hbuf, flags, xccid, verd, histh, histd);
  k_epi1<<<B_, 64, 0, stream>>>(histd, histh, Ws, bs, Wrs, brs, ldis, theme);
  k_epi2<<<dim3(24, 16), 256, 0, stream>>>(histh, ldis, Wc, bc, convb);
  k_epi3<<<B_, 384, 0, stream>>>(theme, convb, histh, Wo, bo, (float*)d_out);
}

// Round 12
// 2035.736 us; speedup vs baseline: 3134.0615x; 3134.0615x over previous
//
// StageNet MI355X r12: scan frozen at r6 (best verified: 1.60ms; r7-r11 all regressed
// or nulled). This round: precast x+time to padded bf16 rows (L3-resident, 59MB) so
// k_pre_gemm stages via short8 loads (no f32 refetch x13, no per-element converts).
// ws-guarded: falls back to the r6 pre-GEMM verbatim if workspace is too small.
#include <hip/hip_runtime.h>
#include <hip/hip_bf16.h>
#include <stdint.h>

#define B_  256
#define T_  400
#define D_  280
#define H_  384
#define L_  12
#define K_  10
#define G_  1560
#define NP_ 1568
#define NT_USED 98
#define NT_PAD  104

typedef __attribute__((ext_vector_type(8))) short  short8_t;
typedef __attribute__((ext_vector_type(4))) float  float4_t;

__device__ __forceinline__ unsigned short f2bf(float f) {
  union { __hip_bfloat16 h; unsigned short u; } cv;
  cv.h = __float2bfloat16(f);
  return cv.u;
}
__device__ __forceinline__ float bf2f_lo(uint32_t u) { return __uint_as_float(u << 16); }
__device__ __forceinline__ float bf2f_hi(uint32_t u) { return __uint_as_float(u & 0xffff0000u); }
__device__ __forceinline__ float sigm(float x) { return 1.f / (1.f + __expf(-x)); }
__device__ __forceinline__ float ftanh(float x) { return 1.f - 2.f / (__expf(2.f * x) + 1.f); }

__device__ __forceinline__ int perm_g(int p) {
  if (p < 0 || p >= 32 + 12 * 128) return -1;
  if (p < 24) return p;
  if (p < 32) return -1;
  int q = p - 32;
  int l = q >> 7, r = q & 127, jb = r >> 5, cc = r & 31;
  return 24 + ((jb * 12 + l) << 5) + cc;
}

// ---------------- P0a: build WkbF + bias ----------------
__global__ void k_build_wkbf(const float* __restrict__ Wk, const float* __restrict__ bk,
                             const float* __restrict__ Wr, const float* __restrict__ br,
                             uint4* __restrict__ wkbF, float* __restrict__ bias) {
  int idx  = blockIdx.x * 256 + threadIdx.x;
  int lane = idx & 63;
  int rest = idx >> 6;
  int kt = rest % 9, nt = rest / 9;
  if (nt >= NT_PAD) return;
  int p = nt * 16 + (lane & 15);
  int g = perm_g(p);
  int kbase = kt * 32 + ((lane >> 4) << 3);
  unsigned short v[8];
#pragma unroll
  for (int j = 0; j < 8; ++j) {
    int k = kbase + j;
    float val = 0.f;
    if (g >= 0) {
      if (k < 280)        val = Wk[(size_t)k * G_ + g];
      else if (k == 280)  val = Wk[(size_t)280 * G_ + g] + Wr[(size_t)384 * G_ + g];
    }
    v[j] = f2bf(val);
  }
  uint4 u;
  u.x = (uint32_t)v[0] | ((uint32_t)v[1] << 16);
  u.y = (uint32_t)v[2] | ((uint32_t)v[3] << 16);
  u.z = (uint32_t)v[4] | ((uint32_t)v[5] << 16);
  u.w = (uint32_t)v[6] | ((uint32_t)v[7] << 16);
  wkbF[(size_t)(nt * 9 + kt) * 64 + lane] = u;
  if (kt == 0 && (lane >> 4) == 0 && p < NP_)
    bias[p] = (g >= 0) ? (bk[g] + br[g]) : 0.f;
}

// ---------------- P0c: build WrF ----------------
__global__ void k_build_wrf(const float* __restrict__ Wr, uint4* __restrict__ wrF) {
  int idx  = blockIdx.x * 256 + threadIdx.x;
  int lane = idx & 63;
  int rest = idx >> 6;
  int kt = rest % 12, nt = rest / 12;
  if (nt >= NT_USED) return;
  int p = nt * 16 + (lane & 15);
  int g = perm_g(p);
  int kbase = kt * 32 + ((lane >> 4) << 3);
  unsigned short v[8];
#pragma unroll
  for (int j = 0; j < 8; ++j) {
    int k = kbase + j;
    float val = (g >= 0) ? Wr[(size_t)k * G_ + g] : 0.f;
    v[j] = f2bf(val);
  }
  uint4 u;
  u.x = (uint32_t)v[0] | ((uint32_t)v[1] << 16);
  u.y = (uint32_t)v[2] | ((uint32_t)v[3] << 16);
  u.z = (uint32_t)v[4] | ((uint32_t)v[5] << 16);
  u.w = (uint32_t)v[6] | ((uint32_t)v[7] << 16);
  wrF[(size_t)(nt * 12 + kt) * 64 + lane] = u;
}

// ---------------- P0x: precast x+time -> bf16 rows [B*T][288] (281..287 = 0) ----------------
__global__ void k_precast(const float* __restrict__ x, const float* __restrict__ timev,
                          unsigned short* __restrict__ xb) {
  int idx = blockIdx.x * 256 + threadIdx.x;      // B*T*36 = 3,686,400 exact
  int bt = idx / 36, kc = idx % 36;
  const float* xr = x + (size_t)bt * D_;
  int k0 = kc * 8;
  unsigned short v[8];
#pragma unroll
  for (int j = 0; j < 8; ++j) {
    int k = k0 + j;
    float val = 0.f;
    if (k < 280)       val = xr[k];
    else if (k == 280) val = timev[bt];
    v[j] = f2bf(val);
  }
  uint4 u;
  u.x = (uint32_t)v[0] | ((uint32_t)v[1] << 16);
  u.y = (uint32_t)v[2] | ((uint32_t)v[3] << 16);
  u.z = (uint32_t)v[4] | ((uint32_t)v[5] << 16);
  u.w = (uint32_t)v[6] | ((uint32_t)v[7] << 16);
  *(uint4*)(xb + (size_t)bt * 288 + k0) = u;
}

// ---------------- P1 (fast): pre-projection GEMM from precast bf16 ----------------
__global__ __launch_bounds__(256) void k_pre_gemm2(
    const unsigned short* __restrict__ xb,
    const uint4* __restrict__ wkbF, const float* __restrict__ bias,
    uint2* __restrict__ preF) {
  __shared__ unsigned short A_lds[128 * 40];
  __shared__ uint4 B_lds[8 * 64];
  const int tid = threadIdx.x;
  const int ntile = blockIdx.x;
  const int tm = blockIdx.y;
  const int t = tm >> 1, b0 = (tm & 1) << 7;
  const int wv = tid >> 6, lane = tid & 63;
  const int wr = wv >> 1, wc = wv & 1;
  float4_t acc[4][4];
#pragma unroll
  for (int fi = 0; fi < 4; ++fi)
#pragma unroll
    for (int fj = 0; fj < 4; ++fj) { acc[fi][fj][0]=0.f; acc[fi][fj][1]=0.f; acc[fi][fj][2]=0.f; acc[fi][fj][3]=0.f; }

  for (int kt = 0; kt < 9; ++kt) {
    {
      int mi = tid >> 1, half = tid & 1, kk0 = half * 16;
      const unsigned short* src = xb + ((size_t)(b0 + mi) * T_ + t) * 288 + kt * 32 + kk0;
      short8_t v0 = *(const short8_t*)src;
      short8_t v1 = *(const short8_t*)(src + 8);
      unsigned short* dst = &A_lds[mi * 40 + kk0];
      *(short8_t*)dst = v0;
      *(short8_t*)(dst + 8) = v1;
    }
#pragma unroll
    for (int pz = 0; pz < 2; ++pz) {
      int fn = (tid >> 6) + pz * 4;
      int inner = tid & 63;
      int ntg = ntile * 8 + fn;
      B_lds[fn * 64 + inner] = wkbF[(size_t)(ntg * 9 + kt) * 64 + inner];
    }
    __syncthreads();
    short8_t a[4], bfr[4];
#pragma unroll
    for (int fi = 0; fi < 4; ++fi) {
      int m = wr * 64 + fi * 16 + (lane & 15);
      a[fi] = *(const short8_t*)&A_lds[m * 40 + ((lane >> 4) << 3)];
    }
#pragma unroll
    for (int fj = 0; fj < 4; ++fj) {
      uint4 u = B_lds[(wc * 4 + fj) * 64 + lane];
      bfr[fj] = *reinterpret_cast<short8_t*>(&u);
    }
#pragma unroll
    for (int fi = 0; fi < 4; ++fi)
#pragma unroll
      for (int fj = 0; fj < 4; ++fj)
        acc[fi][fj] = __builtin_amdgcn_mfma_f32_16x16x32_bf16(a[fi], bfr[fj], acc[fi][fj], 0, 0, 0);
    __syncthreads();
  }
#pragma unroll
  for (int fi = 0; fi < 4; ++fi)
#pragma unroll
    for (int fj = 0; fj < 4; ++fj) {
      int nt_g = ntile * 8 + wc * 4 + fj;
      if (nt_g < NT_USED) {
        int bg = (b0 >> 4) + wr * 4 + fi;
        float bv = bias[nt_g * 16 + (lane & 15)];
        unsigned short r0 = f2bf(acc[fi][fj][0] + bv);
        unsigned short r1 = f2bf(acc[fi][fj][1] + bv);
        unsigned short r2 = f2bf(acc[fi][fj][2] + bv);
        unsigned short r3 = f2bf(acc[fi][fj][3] + bv);
        uint2 u;
        u.x = (uint32_t)r0 | ((uint32_t)r1 << 16);
        u.y = (uint32_t)r2 | ((uint32_t)r3 << 16);
        preF[(((size_t)t * 16 + bg) * NT_USED + nt_g) * 64 + lane] = u;
      }
    }
}

// ---------------- P1 (fallback): r6 pre-GEMM verbatim ----------------
__global__ __launch_bounds__(256) void k_pre_gemm(
    const float* __restrict__ x, const float* __restrict__ timev,
    const uint4* __restrict__ wkbF, const float* __restrict__ bias,
    uint2* __restrict__ preF) {
  __shared__ unsigned short A_lds[128 * 40];
  __shared__ uint4 B_lds[8 * 64];
  const int tid = threadIdx.x;
  const int ntile = blockIdx.x;
  const int tm = blockIdx.y;
  const int t = tm >> 1, b0 = (tm & 1) << 7;
  const int wv = tid >> 6, lane = tid & 63;
  const int wr = wv >> 1, wc = wv & 1;
  float4_t acc[4][4];
#pragma unroll
  for (int fi = 0; fi < 4; ++fi)
#pragma unroll
    for (int fj = 0; fj < 4; ++fj) { acc[fi][fj][0]=0.f; acc[fi][fj][1]=0.f; acc[fi][fj][2]=0.f; acc[fi][fj][3]=0.f; }

  for (int kt = 0; kt < 9; ++kt) {
    {
      int mi = tid >> 1, half = tid & 1, kk0 = half * 16;
      int b = b0 + mi;
      const float* xrow = x + ((size_t)b * T_ + t) * D_;
      int k0 = kt * 32 + kk0;
      unsigned short* dst = &A_lds[mi * 40 + kk0];
      if (kt < 8) {
        float4 v0 = *(const float4*)(xrow + k0);
        float4 v1 = *(const float4*)(xrow + k0 + 4);
        float4 v2 = *(const float4*)(xrow + k0 + 8);
        float4 v3 = *(const float4*)(xrow + k0 + 12);
        dst[0]=f2bf(v0.x); dst[1]=f2bf(v0.y); dst[2]=f2bf(v0.z); dst[3]=f2bf(v0.w);
        dst[4]=f2bf(v1.x); dst[5]=f2bf(v1.y); dst[6]=f2bf(v1.z); dst[7]=f2bf(v1.w);
        dst[8]=f2bf(v2.x); dst[9]=f2bf(v2.y); dst[10]=f2bf(v2.z); dst[11]=f2bf(v2.w);
        dst[12]=f2bf(v3.x); dst[13]=f2bf(v3.y); dst[14]=f2bf(v3.z); dst[15]=f2bf(v3.w);
      } else {
#pragma unroll
        for (int e = 0; e < 16; ++e) {
          int k = k0 + e;
          float val = 0.f;
          if (k < 280)       val = xrow[k];
          else if (k == 280) val = timev[(size_t)b * T_ + t];
          dst[e] = f2bf(val);
        }
      }
    }
#pragma unroll
    for (int pz = 0; pz < 2; ++pz) {
      int fn = (tid >> 6) + pz * 4;
      int inner = tid & 63;
      int ntg = ntile * 8 + fn;
      B_lds[fn * 64 + inner] = wkbF[(size_t)(ntg * 9 + kt) * 64 + inner];
    }
    __syncthreads();
    short8_t a[4], bfr[4];
#pragma unroll
    for (int fi = 0; fi < 4; ++fi) {
      int m = wr * 64 + fi * 16 + (lane & 15);
      a[fi] = *(const short8_t*)&A_lds[m * 40 + ((lane >> 4) << 3)];
    }
#pragma unroll
    for (int fj = 0; fj < 4; ++fj) {
      uint4 u = B_lds[(wc * 4 + fj) * 64 + lane];
      bfr[fj] = *reinterpret_cast<short8_t*>(&u);
    }
#pragma unroll
    for (int fi = 0; fi < 4; ++fi)
#pragma unroll
      for (int fj = 0; fj < 4; ++fj)
        acc[fi][fj] = __builtin_amdgcn_mfma_f32_16x16x32_bf16(a[fi], bfr[fj], acc[fi][fj], 0, 0, 0);
    __syncthreads();
  }
#pragma unroll
  for (int fi = 0; fi < 4; ++fi)
#pragma unroll
    for (int fj = 0; fj < 4; ++fj) {
      int nt_g = ntile * 8 + wc * 4 + fj;
      if (nt_g < NT_USED) {
        int bg = (b0 >> 4) + wr * 4 + fi;
        float bv = bias[nt_g * 16 + (lane & 15)];
        unsigned short r0 = f2bf(acc[fi][fj][0] + bv);
        unsigned short r1 = f2bf(acc[fi][fj][1] + bv);
        unsigned short r2 = f2bf(acc[fi][fj][2] + bv);
        unsigned short r3 = f2bf(acc[fi][fj][3] + bv);
        uint2 u;
        u.x = (uint32_t)r0 | ((uint32_t)r1 << 16);
        u.y = (uint32_t)r2 | ((uint32_t)r3 << 16);
        preF[(((size_t)t * 16 + bg) * NT_USED + nt_g) * 64 + lane] = u;
      }
    }
}

// ---------------- Scan: r6 verbatim (best verified) ----------------
#define XOS 164
#define WLDS_B   (10 * 12 * 64 * 16)          // 122880
#define XOL_OFF  WLDS_B
#define CST_OFF  (XOL_OFF + 16 * XOS * 4)     // +10496
#define FMV_OFF  (CST_OFF + 16 * 32 * 4)      // +2048
#define IMV_OFF  (FMV_OFF + 64)
#define SMEM_B   (IMV_OFF + 64)               // 135616 total
__global__ __launch_bounds__(256, 1)
void k_scan(
    const uint2* __restrict__ preF, const uint4* __restrict__ wrF,
    uint32_t* __restrict__ hbuf, uint32_t* __restrict__ flags,
    float* __restrict__ hist_h, float* __restrict__ hist_dis) {
  extern __shared__ char smem[];
  uint4* wLDS = (uint4*)smem;                         // [10 tiles][12 kt][64 lanes]
  float (*xoL)[XOS] = (float(*)[XOS])(smem + XOL_OFF);
  float (*cSt)[32]  = (float(*)[32])(smem + CST_OFF);
  float* fmv = (float*)(smem + FMV_OFF);
  float* imv = (float*)(smem + IMV_OFF);

  const int tid  = threadIdx.x;
  const int wv   = tid >> 6, lane = tid & 63;
  const int bid  = blockIdx.x;
  const int l_own = bid >> 4, bg = bid & 15;
  const int nT = (wv < 2) ? 3 : 2;
  int ltg[3], ntg[3];
#pragma unroll
  for (int i = 0; i < 3; ++i) {
    int lt = wv + 4 * i;
    ltg[i] = lt;
    ntg[i] = (lt < 2) ? lt : (2 + 8 * l_own + (lt - 2));
  }
#pragma unroll
  for (int i = 0; i < 3; ++i) {
    if (i < nT) {
#pragma unroll
      for (int kt = 0; kt < 12; ++kt)
        wLDS[(ltg[i] * 12 + kt) * 64 + lane] = wrF[(size_t)(ntg[i] * 12 + kt) * 64 + lane];
    }
  }
  { int b = tid >> 4, cp = tid & 15; cSt[b][cp * 2] = 0.f; cSt[b][cp * 2 + 1] = 0.f; }
  __syncthreads();

  const int rr0 = lane >> 4;
  const int cN  = lane & 15;
  for (int t = 0; t < T_; ++t) {
    float4_t acc[3];
#pragma unroll
    for (int i = 0; i < 3; ++i) {
      if (i < nT) {
        uint2 p = preF[(((size_t)t * 16 + bg) * NT_USED + ntg[i]) * 64 + lane];
        acc[i][0] = bf2f_lo(p.x); acc[i][1] = bf2f_hi(p.x);
        acc[i][2] = bf2f_lo(p.y); acc[i][3] = bf2f_hi(p.y);
      }
    }
    if (t > 0) {
      const uint32_t need = (uint32_t)t;
      const bool lact = lane < 12;
      const uint32_t* fp = flags + bg * 32 + (lact ? lane : 0);
      int budget = 200000;
      bool ok = false;
      while (!ok && budget-- > 0) {
        uint32_t v = __hip_atomic_load(fp, __ATOMIC_RELAXED, __HIP_MEMORY_SCOPE_AGENT);
        ok = __all(!lact || v >= need);
      }
    }
    __builtin_amdgcn_sched_barrier(0);
    asm volatile("" ::: "memory");
    const int slot = t & 1;
    short8_t af[12];
#pragma unroll
    for (int kt = 0; kt < 12; ++kt) {
      const unsigned long long* hp =
          (const unsigned long long*)(hbuf + (((slot * 16 + bg) * 12 + kt) << 8) + lane * 4);
      unsigned long long u0 = __hip_atomic_load(hp + 0, __ATOMIC_RELAXED, __HIP_MEMORY_SCOPE_AGENT);
      unsigned long long u1 = __hip_atomic_load(hp + 1, __ATOMIC_RELAXED, __HIP_MEMORY_SCOPE_AGENT);
      uint4 u;
      u.x = (uint32_t)u0; u.y = (uint32_t)(u0 >> 32);
      u.z = (uint32_t)u1; u.w = (uint32_t)(u1 >> 32);
      af[kt] = *reinterpret_cast<short8_t*>(&u);
    }
#pragma unroll
    for (int kt = 0; kt < 12; ++kt) {
#pragma unroll
      for (int i = 0; i < 3; ++i) {
        if (i < nT) {
          uint4 w = wLDS[(ltg[i] * 12 + kt) * 64 + lane];
          acc[i] = __builtin_amdgcn_mfma_f32_16x16x32_bf16(af[kt], *reinterpret_cast<short8_t*>(&w), acc[i], 0, 0, 0);
        }
      }
    }
#pragma unroll
    for (int i = 0; i < 3; ++i) {
      if (i < nT && ltg[i] < 10) {
#pragma unroll
        for (int r = 0; r < 4; ++r)
          xoL[rr0 * 4 + r][ltg[i] * 16 + cN] = acc[i][r];
      }
    }
    __syncthreads();
    if (tid < 32) {
      int b = tid & 15;
      int base = (tid < 16) ? 0 : 12;
      float v[12], mx = -1e30f;
#pragma unroll
      for (int j = 0; j < 12; ++j) { v[j] = xoL[b][base + j]; mx = fmaxf(mx, v[j]); }
      float e[12], s = 0.f;
#pragma unroll
      for (int j = 0; j < 12; ++j) { e[j] = __expf(v[j] - mx); s += e[j]; }
      float inv = 1.f / s;
      if (tid < 16) {
        float cum = 0.f, fml = 0.f, fsum = 0.f;
#pragma unroll
        for (int j = 0; j < 12; ++j) {
          cum += e[j] * inv;
          if (j == l_own) fml = cum;
          fsum += cum;
        }
        fmv[b] = fml;
        if (l_own == 0 && t >= T_ - K_)
          hist_dis[(t - (T_ - K_)) * B_ + bg * 16 + b] = 1.f - fsum * (1.f / 12.f);
      } else {
        float cum = 0.f, iml = 0.f;
#pragma unroll
        for (int j = 11; j >= 0; --j) {
          cum += e[j] * inv;
          if (j == l_own) iml = cum;
        }
        imv[b] = iml;
      }
    }
    __syncthreads();
    {
      int b = tid >> 4, cp = tid & 15, c0 = cp << 1;
      float fm_ = fmv[b], im_ = imv[b], ov = fm_ * im_;
      uint32_t packed = 0;
      float hh[2];
#pragma unroll
      for (int e2 = 0; e2 < 2; ++e2) {
        int c = c0 + e2;
        float f  = sigm(xoL[b][32 + c]);
        float ii = sigm(xoL[b][64 + c]);
        float oo = sigm(xoL[b][96 + c]);
        float ci = ftanh(xoL[b][128 + c]);
        float cl = cSt[b][c];
        float cn = ov * (f * cl + ii * ci) + (fm_ - ov) * cl + (im_ - ov) * ci;
        cSt[b][c] = cn;
        float h = oo * ftanh(cn);
        hh[e2] = h;
        packed |= (uint32_t)f2bf(h) << (16 * e2);
      }
      int hl = b + ((c0 >> 3) << 4);
      int slot2 = (t + 1) & 1;
      uint32_t* hp = hbuf + (((slot2 * 16 + bg) * 12 + l_own) << 8) + hl * 4 + ((c0 & 7) >> 1);
      __hip_atomic_store(hp, packed, __ATOMIC_RELAXED, __HIP_MEMORY_SCOPE_AGENT);
      if (t >= T_ - K_) {
        float* hd = hist_h + (((size_t)(t - (T_ - K_)) * B_) + bg * 16 + b) * H_ + l_own * 32 + c0;
        hd[0] = hh[0]; hd[1] = hh[1];
      }
    }
    __syncthreads();
    if (tid == 0 && t < T_ - 1)
      __hip_atomic_store(flags + bg * 32 + l_own, (uint32_t)(t + 1),
                         __ATOMIC_RELAXED, __HIP_MEMORY_SCOPE_AGENT);
  }
}

// ---------------- E1: local_dis + theme ----------------
__global__ void k_epi1(const float* __restrict__ hist_dis, const float* __restrict__ hist_h,
                       const float* __restrict__ Ws, const float* __restrict__ bs,
                       const float* __restrict__ Wrs, const float* __restrict__ brs,
                       float* __restrict__ ldis, float* __restrict__ theme) {
  int b = blockIdx.x, tid = threadIdx.x;  // 64 threads
  __shared__ float ld_s[K_], mh[H_], t1[64];
  if (tid == 0) {
    float cum = 0.f, v[K_], mx = -1e30f;
#pragma unroll
    for (int k = 0; k < K_; ++k) { cum += hist_dis[k * B_ + b]; v[k] = cum; mx = fmaxf(mx, cum); }
    float e[K_], s = 0.f;
#pragma unroll
    for (int k = 0; k < K_; ++k) { e[k] = __expf(v[k] - mx); s += e[k]; }
    float inv = 1.f / s;
#pragma unroll
    for (int k = 0; k < K_; ++k) { float r = e[k] * inv; ld_s[k] = r; ldis[b * K_ + k] = r; }
  }
  __syncthreads();
  for (int h = tid; h < H_; h += 64) {
    float a = 0.f;
#pragma unroll
    for (int k = 0; k < K_; ++k) a += hist_h[((size_t)k * B_ + b) * H_ + h] * ld_s[k];
    mh[h] = a * 0.1f;
  }
  __syncthreads();
  {
    float a = bs[tid];
    for (int h = 0; h < H_; ++h) a += mh[h] * Ws[h * 64 + tid];
    t1[tid] = fmaxf(a, 0.f);
  }
  __syncthreads();
  for (int o = tid; o < H_; o += 64) {
    float a = brs[o];
#pragma unroll 8
    for (int j = 0; j < 64; ++j) a += t1[j] * Wrs[j * H_ + o];
    theme[b * H_ + o] = sigm(a);
  }
}

// ---------------- E2: conv ----------------
__global__ __launch_bounds__(256) void k_epi2(const float* __restrict__ hist_h,
                                              const float* __restrict__ ldis,
                                              const float* __restrict__ Wc,
                                              const float* __restrict__ bc,
                                              float* __restrict__ convb) {
  __shared__ float lh_s[16][644];
  int og = blockIdx.x, bgp = blockIdx.y, tid = threadIdx.x;
  int b_l = tid & 15, o_l = tid >> 4;
  int b = bgp * 16 + b_l, o = og * 16 + o_l;
  float acc = 0.f;
  for (int c0 = 0; c0 < H_; c0 += 64) {
    __syncthreads();
    for (int it = tid; it < 16 * 64 * K_; it += 256) {
      int bb = it / 640, rem = it % 640, cc = rem / K_, k = rem % K_;
      lh_s[bb][cc * K_ + k] =
          hist_h[((size_t)k * B_ + bgp * 16 + bb) * H_ + c0 + cc] * ldis[(bgp * 16 + bb) * K_ + k];
    }
    __syncthreads();
    const float* wp = Wc + ((size_t)o * H_ + c0) * K_;
    for (int cc = 0; cc < 64; ++cc) {
#pragma unroll
      for (int k = 0; k < K_; ++k) acc += lh_s[b_l][cc * K_ + k] * wp[cc * K_ + k];
    }
  }
  convb[b * H_ + o] = acc + bc[o];
}

// ---------------- E3: final ----------------
__global__ void k_epi3(const float* __restrict__ theme, const float* __restrict__ convb,
                       const float* __restrict__ hist_h, const float* __restrict__ Wo,
                       const float* __restrict__ bo, float* __restrict__ out) {
  int b = blockIdx.x, tid = threadIdx.x;  // 384 threads
  __shared__ float part[6];
  float hfin = hist_h[((size_t)(K_ - 1) * B_ + b) * H_ + tid];
  float v = (theme[b * H_ + tid] * convb[b * H_ + tid] + hfin) * Wo[tid];
#pragma unroll
  for (int off = 32; off >= 1; off >>= 1) v += __shfl_down(v, off, 64);
  if ((tid & 63) == 0) part[tid >> 6] = v;
  __syncthreads();
  if (tid == 0) {
    float s = part[0] + part[1] + part[2] + part[3] + part[4] + part[5];
    out[b] = sigm(s + bo[0]);
  }
}

// ---------------- host ----------------
extern "C" void kernel_launch(void* const* d_in, const int* in_sizes, int n_in,
                              void* d_out, int out_size, void* d_ws, size_t ws_size,
                              hipStream_t stream) {
  const float* x    = (const float*)d_in[0];
  const float* tmv  = (const float*)d_in[1];
  const float* Wk   = (const float*)d_in[2];
  const float* bk   = (const float*)d_in[3];
  const float* Wr   = (const float*)d_in[4];
  const float* br   = (const float*)d_in[5];
  const float* Ws   = (const float*)d_in[6];
  const float* bs   = (const float*)d_in[7];
  const float* Wrs  = (const float*)d_in[8];
  const float* brs  = (const float*)d_in[9];
  const float* Wc   = (const float*)d_in[10];
  const float* bc   = (const float*)d_in[11];
  const float* Wo   = (const float*)d_in[12];
  const float* bo   = (const float*)d_in[13];

  char* ws = (char*)d_ws;
  size_t off = 0;
  auto alloc = [&](size_t bytes) { size_t o = off; off = (off + bytes + 255) & ~(size_t)255; return o; };
  const size_t PREF_B  = (size_t)T_ * 16 * NT_USED * 512;
  const size_t WKBF_B  = (size_t)NT_PAD * 9 * 1024;
  const size_t WRF_B   = (size_t)NT_USED * 12 * 1024;
  const size_t BIAS_B  = (size_t)NP_ * 4;
  const size_t HBUF_B  = (size_t)2 * 16 * 12 * 1024;
  const size_t FLAG_B  = (size_t)16 * 32 * 4;
  const size_t HISTH_B = (size_t)K_ * B_ * H_ * 4;
  const size_t HISTD_B = (size_t)K_ * B_ * 4;
  const size_t LDIS_B  = (size_t)B_ * K_ * 4;
  const size_t THEME_B = (size_t)B_ * H_ * 4;
  const size_t CONV_B  = (size_t)B_ * H_ * 4;
  const size_t XB_B    = (size_t)B_ * T_ * 288 * 2;   // 58,982,400

  size_t o_pref  = alloc(PREF_B);
  size_t o_wkbf  = alloc(WKBF_B);
  size_t o_wrf   = alloc(WRF_B);
  size_t o_bias  = alloc(BIAS_B);
  size_t o_hbuf  = alloc(HBUF_B + FLAG_B);
  size_t o_flag  = o_hbuf + HBUF_B;
  size_t o_hh    = alloc(HISTH_B);
  size_t o_hd    = alloc(HISTD_B);
  size_t o_ld    = alloc(LDIS_B);
  size_t o_th    = alloc(THEME_B);
  size_t o_cv    = alloc(CONV_B);
  size_t off_base = off;
  size_t o_xb    = alloc(XB_B);
  if (ws_size < off_base) return;                 // cannot run at all
  const bool use_precast = (ws_size >= off);      // xb fits -> fast pre-GEMM path

  uint2*    preF  = (uint2*)(ws + o_pref);
  uint4*    wkbF  = (uint4*)(ws + o_wkbf);
  uint4*    wrF   = (uint4*)(ws + o_wrf);
  float*    bias  = (float*)(ws + o_bias);
  uint32_t* hbuf  = (uint32_t*)(ws + o_hbuf);
  uint32_t* flags = (uint32_t*)(ws + o_flag);
  float*    histh = (float*)(ws + o_hh);
  float*    histd = (float*)(ws + o_hd);
  float*    ldis  = (float*)(ws + o_ld);
  float*    theme = (float*)(ws + o_th);
  float*    convb = (float*)(ws + o_cv);
  unsigned short* xb = (unsigned short*)(ws + o_xb);

  hipMemsetAsync(ws + o_hbuf, 0, HBUF_B + FLAG_B, stream);
  k_build_wkbf<<<(NT_PAD * 9 * 64) / 256, 256, 0, stream>>>(Wk, bk, Wr, br, wkbF, bias);
  k_build_wrf<<<(NT_USED * 12 * 64) / 256, 256, 0, stream>>>(Wr, wrF);
  if (use_precast) {
    k_precast<<<(B_ * T_ * 36) / 256, 256, 0, stream>>>(x, tmv, xb);
    k_pre_gemm2<<<dim3(13, T_ * 2), 256, 0, stream>>>(xb, wkbF, bias, preF);
  } else {
    k_pre_gemm<<<dim3(13, T_ * 2), 256, 0, stream>>>(x, tmv, wkbF, bias, preF);
  }
  k_scan<<<192, 256, SMEM_B, stream>>>(preF, wrF, hbuf, flags, histh, histd);
  k_epi1<<<B_, 64, 0, stream>>>(histd, histh, Ws, bs, Wrs, brs, ldis, theme);
  k_epi2<<<dim3(24, 16), 256, 0, stream>>>(histh, ldis, Wc, bc, convb);
  k_epi3<<<B_, 384, 0, stream>>>(theme, convb, histh, Wo, bo, (float*)d_out);
}